// Round 2
// baseline (74447.076 us; speedup 1.0000x reference)
//
#include <hip/hip_runtime.h>
#include <hip/hip_bf16.h>
#include <math.h>

#define TT 512
#define BB 64
#define FF 256
#define HH 1024

// ---------------------------------------------------------------------------
// Transpose x[b][t][f] -> xT[t][f][b]. xT ALIASES d_out (dead until out_proj).
// ---------------------------------------------------------------------------
__global__ __launch_bounds__(256) void k_transpose_x(const float* __restrict__ x,
                                                     float* __restrict__ xT) {
    int t = blockIdx.x;
    for (int idx = threadIdx.x; idx < BB * FF; idx += 256) {
        int b = idx >> 8;
        int f = idx & 255;
        xT[((size_t)t * FF + f) * BB + b] = x[((size_t)b * TT + t) * FF + f];
    }
}

// ---------------------------------------------------------------------------
// One fused LSTM step. Block = 4 hidden units x 4 gates; wave = gate;
// lane = batch. Weights wave-uniform -> SGPR loads; activations [k][b]
// coalesced. Cell update fused via 4KB LDS exchange.
// ---------------------------------------------------------------------------
template <typename AT>
__device__ __forceinline__ void gemm_part(const AT* __restrict__ A,
                                          const float* __restrict__ w0,
                                          const float* __restrict__ w1,
                                          const float* __restrict__ w2,
                                          const float* __restrict__ w3,
                                          int K, int lane,
                                          float& acc0, float& acc1,
                                          float& acc2, float& acc3) {
    for (int k = 0; k < K; k += 16) {
        #pragma unroll
        for (int u = 0; u < 16; ++u) {
            float hv = (float)A[(size_t)(k + u) * BB + lane];
            acc0 = fmaf(w0[k + u], hv, acc0);
            acc1 = fmaf(w1[k + u], hv, acc1);
            acc2 = fmaf(w2[k + u], hv, acc2);
            acc3 = fmaf(w3[k + u], hv, acc3);
        }
    }
}

template <typename AT>
__global__ __launch_bounds__(256) void k_lstm_step(
    const AT* __restrict__ A1, int K1,            // [K1][BB] input slice
    const float* __restrict__ W1,                 // [4H][K1]
    const float* __restrict__ Hprev,              // [HH][BB] fp32
    const float* __restrict__ W2,                 // [4H][HH]
    const float* __restrict__ bias,               // [4H]
    float* __restrict__ Hout,                     // [HH][BB] fp32
    __hip_bfloat16* __restrict__ HoutB,           // optional bf16 copy (or null)
    float* __restrict__ Cbuf)                     // [HH][BB] fp32
{
    __shared__ float gs[4][4][BB];
    const int lane = threadIdx.x & 63;
    const int gate = __builtin_amdgcn_readfirstlane(threadIdx.x >> 6); // 0..3
    const int j0   = blockIdx.x * 4;
    const int row0 = gate * HH + j0;

    float acc0 = bias[row0 + 0];
    float acc1 = bias[row0 + 1];
    float acc2 = bias[row0 + 2];
    float acc3 = bias[row0 + 3];

    {   // input projection
        const float* w0 = W1 + (size_t)(row0 + 0) * K1;
        const float* w1 = W1 + (size_t)(row0 + 1) * K1;
        const float* w2 = W1 + (size_t)(row0 + 2) * K1;
        const float* w3 = W1 + (size_t)(row0 + 3) * K1;
        gemm_part<AT>(A1, w0, w1, w2, w3, K1, lane, acc0, acc1, acc2, acc3);
    }
    {   // recurrent part (always fp32)
        const float* w0 = W2 + (size_t)(row0 + 0) * HH;
        const float* w1 = W2 + (size_t)(row0 + 1) * HH;
        const float* w2 = W2 + (size_t)(row0 + 2) * HH;
        const float* w3 = W2 + (size_t)(row0 + 3) * HH;
        gemm_part<float>(Hprev, w0, w1, w2, w3, HH, lane, acc0, acc1, acc2, acc3);
    }

    gs[gate][0][lane] = acc0;
    gs[gate][1][lane] = acc1;
    gs[gate][2][lane] = acc2;
    gs[gate][3][lane] = acc3;
    __syncthreads();

    {
        int jj = threadIdx.x >> 6;
        int b  = threadIdx.x & 63;
        float iv = gs[0][jj][b];
        float fv = gs[1][jj][b];
        float gv = gs[2][jj][b];
        float ov = gs[3][jj][b];
        iv = 1.0f / (1.0f + __expf(-iv));
        fv = 1.0f / (1.0f + __expf(-fv));
        gv = tanhf(gv);
        ov = 1.0f / (1.0f + __expf(-ov));
        size_t idx = (size_t)(j0 + jj) * BB + b;
        float c  = Cbuf[idx];
        float cn = fv * c + iv * gv;
        Cbuf[idx] = cn;
        float hn = ov * tanhf(cn);
        Hout[idx] = hn;
        if (HoutB) HoutB[idx] = (__hip_bfloat16)hn;
    }
}

// ---------------------------------------------------------------------------
// Output projection for one chunk of C timesteps starting at t0.
// out[b][t0+tl][f] = sum_j chunk[tl][j][b] * Wout[f][j] + bout[f]
// ---------------------------------------------------------------------------
__global__ __launch_bounds__(256) void k_out_proj(
    const float* __restrict__ chunk,  // [C][HH][BB]
    const float* __restrict__ Wout,   // [FF][HH]
    const float* __restrict__ bout,   // [FF]
    float* __restrict__ out,          // [BB][TT][FF]
    int t0)
{
    int tl = blockIdx.x;
    int t  = t0 + tl;
    int fg = blockIdx.y;
    const int lane = threadIdx.x & 63;
    const int wv   = __builtin_amdgcn_readfirstlane(threadIdx.x >> 6);
    const int f0   = fg * 64 + wv * 16;
    const float* a = chunk + (size_t)tl * HH * BB;

    float acc[16];
    #pragma unroll
    for (int i = 0; i < 16; ++i) acc[i] = bout[f0 + i];

    for (int k = 0; k < HH; k += 4) {
        #pragma unroll
        for (int u = 0; u < 4; ++u) {
            float hv = a[(size_t)(k + u) * BB + lane];
            #pragma unroll
            for (int i = 0; i < 16; ++i)
                acc[i] = fmaf(Wout[(size_t)(f0 + i) * HH + k + u], hv, acc[i]);
        }
    }

    float* op = out + ((size_t)lane * TT + t) * FF + f0;
    #pragma unroll
    for (int i = 0; i < 16; i += 4) {
        float4 v = make_float4(acc[i], acc[i + 1], acc[i + 2], acc[i + 3]);
        *(float4*)(op + i) = v;
    }
}

// ---------------------------------------------------------------------------
extern "C" void kernel_launch(void* const* d_in, const int* in_sizes, int n_in,
                              void* d_out, int out_size, void* d_ws, size_t ws_size,
                              hipStream_t stream) {
    const float* x     = (const float*)d_in[0];
    const float* Wih_e = (const float*)d_in[1];
    const float* Whh_e = (const float*)d_in[2];
    const float* b_e   = (const float*)d_in[3];
    const float* Wih_d = (const float*)d_in[4];
    const float* Whh_d = (const float*)d_in[5];
    const float* b_d   = (const float*)d_in[6];
    const float* Wout  = (const float*)d_in[7];
    const float* bout  = (const float*)d_in[8];
    float* out = (float*)d_out;

    const size_t SF   = (size_t)HH * BB;     // 65536 elements per state
    const size_t encF = (size_t)TT * SF;     // 33.5M elements (all enc h)

    float* xT = (float*)d_out;               // scratch alias; dead before out_proj

    // Tier/chunk selection. ws_size is constant across calls -> deterministic.
    int  C     = 64;
    bool tierA = false;
    {
        auto needA = [&](int c) {
            return (encF + (size_t)c * SF + 2 * SF) * sizeof(float);
        };
        auto needB = [&](int c) {
            return encF * sizeof(__hip_bfloat16) + ((size_t)c * SF + 3 * SF) * sizeof(float);
        };
        if      (ws_size >= needA(64)) { tierA = true;  C = 64; }
        else if (ws_size >= needA(16)) { tierA = true;  C = 16; }
        else if (ws_size >= needB(64)) { tierA = false; C = 64; }
        else if (ws_size >= needB(32)) { tierA = false; C = 32; }
        else if (ws_size >= needB(16)) { tierA = false; C = 16; }
        else                           { tierA = false; C = 8;  } // last resort
    }

    k_transpose_x<<<TT, 256, 0, stream>>>(x, xT);

    if (tierA) {
        // layout: encT(fp32) | chunk | h0 | cbuf   (151.5 MB @ C=64)
        float* encT  = (float*)d_ws;
        float* chunk = encT + encF;
        float* h0    = chunk + (size_t)C * SF;
        float* cbuf  = h0 + SF;
        hipMemsetAsync(h0,   0, SF * sizeof(float), stream);
        hipMemsetAsync(cbuf, 0, SF * sizeof(float), stream);

        for (int t = 0; t < TT; ++t) {
            const float* hprev = t ? encT + (size_t)(t - 1) * SF : h0;
            k_lstm_step<float><<<HH / 4, 256, 0, stream>>>(
                xT + (size_t)t * FF * BB, FF, Wih_e, hprev, Whh_e, b_e,
                encT + (size_t)t * SF, (__hip_bfloat16*)nullptr, cbuf);
        }
        for (int t = 0; t < TT; ++t) {
            int l = t % C;
            const float* hprev = (t == 0) ? encT + (size_t)(TT - 1) * SF
                               : (l == 0) ? chunk + (size_t)(C - 1) * SF
                                          : chunk + (size_t)(l - 1) * SF;
            k_lstm_step<float><<<HH / 4, 256, 0, stream>>>(
                encT + (size_t)t * SF, HH, Wih_d, hprev, Whh_d, b_d,
                chunk + (size_t)l * SF, (__hip_bfloat16*)nullptr, cbuf);
            if (l == C - 1)
                k_out_proj<<<dim3(C, 4), 256, 0, stream>>>(chunk, Wout, bout, out,
                                                           t - (C - 1));
        }
    } else {
        // layout: encB(bf16) | chunk | hA | hB | cbuf   (84.7 MB @ C=64)
        __hip_bfloat16* encB = (__hip_bfloat16*)d_ws;
        float* chunk = (float*)(encB + encF);
        float* hA    = chunk + (size_t)C * SF;
        float* hB    = hA + SF;
        float* cbuf  = hB + SF;
        hipMemsetAsync(hA,   0, SF * sizeof(float), stream);
        hipMemsetAsync(cbuf, 0, SF * sizeof(float), stream);

        float* hbuf[2] = { hA, hB };
        for (int t = 0; t < TT; ++t) {
            const float* hprev = hbuf[t & 1];
            float*       hout  = hbuf[(t + 1) & 1];
            k_lstm_step<float><<<HH / 4, 256, 0, stream>>>(
                xT + (size_t)t * FF * BB, FF, Wih_e, hprev, Whh_e, b_e,
                hout, encB + (size_t)t * SF, cbuf);
        }
        // final encoder h is in hbuf[0] == hA (TT even); c_T already in cbuf
        for (int t = 0; t < TT; ++t) {
            int l = t % C;
            const float* hprev = (t == 0) ? hA
                               : (l == 0) ? chunk + (size_t)(C - 1) * SF
                                          : chunk + (size_t)(l - 1) * SF;
            k_lstm_step<__hip_bfloat16><<<HH / 4, 256, 0, stream>>>(
                encB + (size_t)t * SF, HH, Wih_d, hprev, Whh_d, b_d,
                chunk + (size_t)l * SF, (__hip_bfloat16*)nullptr, cbuf);
            if (l == C - 1)
                k_out_proj<<<dim3(C, 4), 256, 0, stream>>>(chunk, Wout, bout, out,
                                                           t - (C - 1));
        }
    }
}